// Round 1
// baseline (1713.761 us; speedup 1.0000x reference)
//
#include <hip/hip_runtime.h>
#include <stdint.h>

// Problem constants (from reference)
#define B_SAMPLES 1024
#define D_IN      1536
#define H_DIM     3072
#define C_OUT     5242
#define N_EXP     11

typedef short  short8  __attribute__((ext_vector_type(8)));
typedef float  float4v __attribute__((ext_vector_type(4)));

// fp32 -> bf16 round-to-nearest-even (matches HW/numpy for non-NaN)
__device__ __forceinline__ unsigned short f2bf(float f) {
  unsigned int u = __float_as_uint(f);
  unsigned int r = (u + 0x7fffu + ((u >> 16) & 1u)) >> 16;
  return (unsigned short)r;
}

// ---------------------------------------------------------------------------
// Kernel 0: compute time-bin per sample, build per-expert contiguous index
// lists. One block of 1024 threads (1 thread per sample).
// ---------------------------------------------------------------------------
__global__ void bin_kernel(const float* __restrict__ mf,
                           int* __restrict__ g_cnt,
                           int* __restrict__ g_off,
                           int* __restrict__ g_idx) {
  __shared__ int cnt[N_EXP], off[N_EXP], cur[N_EXP];
  const int t = threadIdx.x;
  if (t < N_EXP) cnt[t] = 0;
  __syncthreads();
  // EXACT fp32 ops as reference: t = 1.0f - mf; bin = trunc(t / 0.1f)
  float tt = 1.0f - mf[t];
  int bin = (int)(tt / 0.1f);
  bin = min(max(bin, 0), N_EXP - 1);
  atomicAdd(&cnt[bin], 1);
  __syncthreads();
  if (t == 0) {
    int a = 0;
    for (int i = 0; i < N_EXP; i++) { off[i] = a; cur[i] = a; a += cnt[i]; }
  }
  __syncthreads();
  int pos = atomicAdd(&cur[bin], 1);
  g_idx[pos] = t;   // permuted position -> original sample id
  if (t < N_EXP) { g_cnt[t] = cnt[t]; g_off[t] = off[t]; }
}

// ---------------------------------------------------------------------------
// Grouped GEMM: for expert e, C[M_e x N] = A[M_e x K] * W[e][K x N] + bias,
// optional exact GELU + bf16 store (hidden layers) or fp32 scatter store
// (final layer). BM=128 (covers avg M_e=102 in ONE tile -> each weight byte
// read from HBM exactly once), BN=64, BK=32, 256 threads = 4 waves (2x2 of
// 64x32), v_mfma_f32_16x16x32_bf16.
// GATHER: A is fp32 x[1024][K] gathered through g_idx (layer 1).
// else:   A is bf16 permuted activations [1024][K].
// ---------------------------------------------------------------------------
template <int K, int N, bool FINAL, bool GATHER>
__global__ __launch_bounds__(256) void gemm_kernel(
    const void* __restrict__ Araw,
    const float* __restrict__ W,        // [11][K][N] fp32
    const float* __restrict__ bias,     // [11][N]    fp32
    unsigned short* __restrict__ Hout,  // [1024][N] bf16 (if !FINAL)
    float* __restrict__ Out,            // [1024][C_OUT] (if FINAL)
    const int* __restrict__ g_cnt,
    const int* __restrict__ g_off,
    const int* __restrict__ g_idx) {
  const int e = blockIdx.z;
  const int cnt = g_cnt[e];
  const int mt = blockIdx.y;
  if (mt * 128 >= cnt) return;          // uniform early-exit (no syncs yet)
  const int nt  = blockIdx.x;
  const int off = g_off[e];
  const int nb  = nt * 64;

  __shared__ unsigned short sA[128][40]; // BK=32 padded to 40 (bank spread)
  __shared__ unsigned short sB[32][66];  // BN=64 padded to 66 (bank spread)

  const int tid  = threadIdx.x;
  const int lane = tid & 63;
  const int wave = tid >> 6;
  const int wm = (wave >> 1) * 64;  // wave row quadrant
  const int wn = (wave & 1) * 32;   // wave col quadrant
  const int q  = lane >> 4;         // 0..3
  const int ln = lane & 15;

  const float* We = W + (size_t)e * K * N;

  float4v acc[4][2];
#pragma unroll
  for (int i = 0; i < 4; i++)
#pragma unroll
    for (int j = 0; j < 2; j++) acc[i][j] = 0.0f;

  // A staging map: 512 chunks of 8 bf16; chunk c: m=c>>2, k8=(c&3)*8.
  // thread handles c = tid and c = tid+256 (m and m+64, same k8).
  const int m0 = tid >> 2;
  const int k8 = (tid & 3) * 8;
  int arow[2];
#pragma unroll
  for (int i = 0; i < 2; i++) {
    int p = off + mt * 128 + m0 + i * 64;
    p = min(p, B_SAMPLES - 1);          // clamp padding rows (masked later)
    arow[i] = GATHER ? g_idx[p] : p;    // layer1 gathers original x rows
  }
  // B staging map: 1024 float2 chunks; chunk c: kr=c>>5, n2=(c&31)*2.
  const int kr0  = tid >> 5;            // 0..7, +8 per iteration
  const int n2   = (tid & 31) * 2;
  const int colB = nb + n2;
  const bool bok0 = (N % 64 == 0) || (colB < N);
  const bool bok1 = (N % 64 == 0) || (colB + 1 < N);

  for (int k0 = 0; k0 < K; k0 += 32) {
    // ---- stage A (bf16, k-contiguous rows of 40) ----
#pragma unroll
    for (int i = 0; i < 2; i++) {
      uint4 o;
      if (GATHER) {
        const float* Af = (const float*)Araw;
        const float4* ap =
            reinterpret_cast<const float4*>(Af + (size_t)arow[i] * K + k0 + k8);
        float4 v0 = ap[0], v1 = ap[1];
        o.x = (unsigned)f2bf(v0.x) | ((unsigned)f2bf(v0.y) << 16);
        o.y = (unsigned)f2bf(v0.z) | ((unsigned)f2bf(v0.w) << 16);
        o.z = (unsigned)f2bf(v1.x) | ((unsigned)f2bf(v1.y) << 16);
        o.w = (unsigned)f2bf(v1.z) | ((unsigned)f2bf(v1.w) << 16);
      } else {
        const unsigned short* Ah = (const unsigned short*)Araw;
        o = *reinterpret_cast<const uint4*>(Ah + (size_t)arow[i] * K + k0 + k8);
      }
      *reinterpret_cast<uint4*>(&sA[m0 + i * 64][k8]) = o;
    }
    // ---- stage B (fp32 HBM stream -> bf16 LDS) ----
#pragma unroll
    for (int i = 0; i < 4; i++) {
      int kr = kr0 + i * 8;
      const float* srcB = We + (size_t)(k0 + kr) * N + colB;
      float f0 = bok0 ? srcB[0] : 0.0f;
      float f1 = bok1 ? srcB[1] : 0.0f;
      unsigned int packed = (unsigned)f2bf(f0) | ((unsigned)f2bf(f1) << 16);
      *reinterpret_cast<unsigned int*>(&sB[kr][n2]) = packed;
    }
    __syncthreads();

    // ---- fragments + MFMA ----
    short8 afr[4], bfr[2];
#pragma unroll
    for (int i = 0; i < 4; i++)
      afr[i] = *reinterpret_cast<const short8*>(&sA[wm + i * 16 + ln][q * 8]);
#pragma unroll
    for (int j = 0; j < 2; j++) {
      short8 b;
#pragma unroll
      for (int jj = 0; jj < 8; jj++)
        b[jj] = (short)sB[q * 8 + jj][wn + j * 16 + ln];
      bfr[j] = b;
    }
#pragma unroll
    for (int i = 0; i < 4; i++)
#pragma unroll
      for (int j = 0; j < 2; j++)
        acc[i][j] = __builtin_amdgcn_mfma_f32_16x16x32_bf16(afr[i], bfr[j],
                                                            acc[i][j], 0, 0, 0);
    __syncthreads();
  }

  // ---- epilogue: bias (+GELU/bf16 store) or (bias + scatter fp32) ----
  // C/D layout (m89): col = lane&15, row = (lane>>4)*4 + reg
  const float* be = bias + (size_t)e * N;
#pragma unroll
  for (int j = 0; j < 2; j++) {
    int col = nb + wn + j * 16 + ln;
    bool colok = (N % 64 == 0) || (col < N);
    float bv = colok ? be[col] : 0.0f;
#pragma unroll
    for (int i = 0; i < 4; i++) {
#pragma unroll
      for (int r = 0; r < 4; r++) {
        int rrel = mt * 128 + wm + i * 16 + q * 4 + r;
        if (rrel < cnt && colok) {
          float v = acc[i][j][r] + bv;
          if (FINAL) {
            int orow = g_idx[off + rrel];
            Out[(size_t)orow * C_OUT + col] = v;
          } else {
            // exact GELU: 0.5*x*(1+erf(x/sqrt(2)))
            float g = 0.5f * v * (1.0f + erff(v * 0.70710678118654752440f));
            Hout[(size_t)(off + rrel) * N + col] = f2bf(g);
          }
        }
      }
    }
  }
}

// ---------------------------------------------------------------------------
// log_softmax in place, one block per row of 5242
// ---------------------------------------------------------------------------
__global__ __launch_bounds__(256) void lsm_kernel(float* __restrict__ out) {
  const int row = blockIdx.x;
  float* p = out + (size_t)row * C_OUT;
  __shared__ float sred[4];
  __shared__ float sval;
  const int tid = threadIdx.x;
  const int lane = tid & 63, wave = tid >> 6;

  float m = -3.4e38f;
  for (int c = tid; c < C_OUT; c += 256) m = fmaxf(m, p[c]);
#pragma unroll
  for (int s = 32; s > 0; s >>= 1) m = fmaxf(m, __shfl_xor(m, s, 64));
  if (lane == 0) sred[wave] = m;
  __syncthreads();
  if (tid == 0) sval = fmaxf(fmaxf(sred[0], sred[1]), fmaxf(sred[2], sred[3]));
  __syncthreads();
  const float M = sval;

  float s = 0.0f;
  for (int c = tid; c < C_OUT; c += 256) s += expf(p[c] - M);
#pragma unroll
  for (int sh = 32; sh > 0; sh >>= 1) s += __shfl_xor(s, sh, 64);
  if (lane == 0) sred[wave] = s;
  __syncthreads();
  if (tid == 0) sval = M + logf(sred[0] + sred[1] + sred[2] + sred[3]);
  __syncthreads();
  const float L = sval;
  for (int c = tid; c < C_OUT; c += 256) p[c] = p[c] - L;
}

// ---------------------------------------------------------------------------
extern "C" void kernel_launch(void* const* d_in, const int* in_sizes, int n_in,
                              void* d_out, int out_size, void* d_ws,
                              size_t ws_size, hipStream_t stream) {
  const float* x  = (const float*)d_in[0];
  const float* mf = (const float*)d_in[1];
  const float* W1 = (const float*)d_in[2];
  const float* b1 = (const float*)d_in[3];
  const float* W2 = (const float*)d_in[4];
  const float* b2 = (const float*)d_in[5];
  const float* W3 = (const float*)d_in[6];
  const float* b3 = (const float*)d_in[7];
  float* out = (float*)d_out;

  // workspace carve (conservative: ~6.3 MB)
  char* ws = (char*)d_ws;
  int* g_cnt = (int*)(ws + 0);
  int* g_off = (int*)(ws + 64);
  int* g_idx = (int*)(ws + 128);                       // 1024 ints
  unsigned short* h2p = (unsigned short*)(ws + 8192);  // [1024][H] bf16

  // h1 lives in d_out (21.5MB fp32 buffer; h1 needs only 6.3MB bf16 and is
  // dead before the final layer overwrites d_out with logits)
  unsigned short* h1p = (unsigned short*)d_out;

  bin_kernel<<<1, B_SAMPLES, 0, stream>>>(mf, g_cnt, g_off, g_idx);

  gemm_kernel<D_IN, H_DIM, false, true>
      <<<dim3(H_DIM / 64, 8, N_EXP), 256, 0, stream>>>(
          x, W1, b1, h1p, nullptr, g_cnt, g_off, g_idx);

  gemm_kernel<H_DIM, H_DIM, false, false>
      <<<dim3(H_DIM / 64, 8, N_EXP), 256, 0, stream>>>(
          h1p, W2, b2, h2p, nullptr, g_cnt, g_off, g_idx);

  gemm_kernel<H_DIM, C_OUT, true, false>
      <<<dim3((C_OUT + 63) / 64, 8, N_EXP), 256, 0, stream>>>(
          h2p, W3, b3, nullptr, out, g_cnt, g_off, g_idx);

  lsm_kernel<<<B_SAMPLES, 256, 0, stream>>>(out);
}